// Round 9
// baseline (1994.978 us; speedup 1.0000x reference)
//
#include <hip/hip_runtime.h>
#include <math.h>

#define BB 2
#define LL 2048
#define DM 1024
#define NH 16
#define HD 64

__device__ __forceinline__ unsigned mono32(float f) {
    unsigned u = __float_as_uint(f);
    return (u & 0x80000000u) ? ~u : (u | 0x80000000u);
}
__device__ __forceinline__ float unmono32(unsigned m) {
    const unsigned u = (m & 0x80000000u) ? (m & 0x7FFFFFFFu) : ~m;
    return __uint_as_float(u);
}

// ---------------------------------------------------------------------------
// 1024x1024 transpose: out[k][n] = in[n][k]
// ---------------------------------------------------------------------------
__global__ __launch_bounds__(256) void transpose1024(
    const float* __restrict__ in, float* __restrict__ out)
{
    __shared__ float t[32][33];
    const int bx = blockIdx.x * 32, by = blockIdx.y * 32;
    const int tx = threadIdx.x & 31, ty = threadIdx.x >> 5;
    for (int r = ty; r < 32; r += 8)
        t[r][tx] = in[(size_t)(by + r) * DM + bx + tx];
    __syncthreads();
    for (int r = ty; r < 32; r += 8)
        out[(size_t)(bx + r) * DM + by + tx] = t[tx][r];
}

// ---------------------------------------------------------------------------
// Bit-emulated f32 projection (numpy -> OpenBLAS sgemm, Zen/Haswell):
// K-panels (384,320,320); serial ascending-k FMA chain per panel; C += panel;
// then +bias. Scatter to [B,H,L,D]. Wt is W transposed [k][n].
// v2: 4 columns/thread (float4 W loads) + float4 LDS x reads; per-output
// fmaf chain IDENTICAL (k ascending per (m,n), panel C+= order kept).
// DO NOT TOUCH chain order: Q/K bit-exactness determines top-k selection.
// ---------------------------------------------------------------------------
__global__ __launch_bounds__(256) void proj_emul(
    const float* __restrict__ x, const float* __restrict__ Wt,
    const float* __restrict__ bias, float* __restrict__ outp)
{
    __shared__ float xs[8][DM];   // 32 KB
    const int tid = threadIdx.x;
    const int n4  = tid * 4;                 // 4 consecutive cols per thread
    const int m0  = blockIdx.x * 8;

    for (int i = tid; i < 8 * 256; i += 256) {
        const int r = i >> 8, c4 = (i & 255) << 2;
        *(float4*)&xs[r][c4] = *(const float4*)&x[(size_t)(m0 + r) * DM + c4];
    }
    __syncthreads();

    const int kbound[4] = {0, 384, 704, 1024};   // OpenBLAS Zen panel splits

    float S[8][4] = {};
#pragma unroll
    for (int p = 0; p < 3; p++) {
        float P[8][4] = {};
        for (int k = kbound[p]; k < kbound[p + 1]; k += 4) {
            const float4 w0 = *(const float4*)&Wt[(size_t)(k + 0) * DM + n4];
            const float4 w1 = *(const float4*)&Wt[(size_t)(k + 1) * DM + n4];
            const float4 w2 = *(const float4*)&Wt[(size_t)(k + 2) * DM + n4];
            const float4 w3 = *(const float4*)&Wt[(size_t)(k + 3) * DM + n4];
#pragma unroll
            for (int m = 0; m < 8; m++) {
                const float4 xv = *(const float4*)&xs[m][k];
                P[m][0] = fmaf(xv.x, w0.x, P[m][0]);
                P[m][1] = fmaf(xv.x, w0.y, P[m][1]);
                P[m][2] = fmaf(xv.x, w0.z, P[m][2]);
                P[m][3] = fmaf(xv.x, w0.w, P[m][3]);
                P[m][0] = fmaf(xv.y, w1.x, P[m][0]);
                P[m][1] = fmaf(xv.y, w1.y, P[m][1]);
                P[m][2] = fmaf(xv.y, w1.z, P[m][2]);
                P[m][3] = fmaf(xv.y, w1.w, P[m][3]);
                P[m][0] = fmaf(xv.z, w2.x, P[m][0]);
                P[m][1] = fmaf(xv.z, w2.y, P[m][1]);
                P[m][2] = fmaf(xv.z, w2.z, P[m][2]);
                P[m][3] = fmaf(xv.z, w2.w, P[m][3]);
                P[m][0] = fmaf(xv.w, w3.x, P[m][0]);
                P[m][1] = fmaf(xv.w, w3.y, P[m][1]);
                P[m][2] = fmaf(xv.w, w3.z, P[m][2]);
                P[m][3] = fmaf(xv.w, w3.w, P[m][3]);
            }
        }
#pragma unroll
        for (int m = 0; m < 8; m++) {
#pragma unroll
            for (int j = 0; j < 4; j++) S[m][j] += P[m][j];  // C += panel
        }
    }

    const float4 b4v = *(const float4*)&bias[n4];
    const int h = n4 / HD, d0 = n4 % HD;   // 4 cols stay in one head
#pragma unroll
    for (int m = 0; m < 8; m++) {
        const int mm = m0 + m;
        const int b = mm / LL, l = mm % LL;
        float4 o;
        o.x = S[m][0] + b4v.x; o.y = S[m][1] + b4v.y;
        o.z = S[m][2] + b4v.z; o.w = S[m][3] + b4v.w;
        *(float4*)&outp[(((size_t)b * NH + h) * LL + l) * HD + d0] = o;
    }
}

// ---------------------------------------------------------------------------
// f32 GEMM for V (MODE 0 scatter) and output projection (MODE 1).
// ---------------------------------------------------------------------------
template <int MODE>
__global__ __launch_bounds__(256) void gemm_f32(
    const float* __restrict__ A, const float* __restrict__ W,
    const float* __restrict__ bias, float* __restrict__ out,
    int M, int N, int K)
{
    __shared__ float As[16][64];
    __shared__ float Bs[16][64];
    const int tid = threadIdx.x;
    const int m0 = blockIdx.y * 64;
    const int n0 = blockIdx.x * 64;
    const int tx = tid & 15, ty = tid >> 4;
    const int lr = tid >> 2, lc = (tid & 3) * 4;

    float acc[4][4] = {};

    for (int k0 = 0; k0 < K; k0 += 16) {
        float4 a4 = *(const float4*)&A[(size_t)(m0 + lr) * K + k0 + lc];
        float4 b4 = *(const float4*)&W[(size_t)(n0 + lr) * K + k0 + lc];
        __syncthreads();
        As[lc + 0][lr] = a4.x; As[lc + 1][lr] = a4.y;
        As[lc + 2][lr] = a4.z; As[lc + 3][lr] = a4.w;
        Bs[lc + 0][lr] = b4.x; Bs[lc + 1][lr] = b4.y;
        Bs[lc + 2][lr] = b4.z; Bs[lc + 3][lr] = b4.w;
        __syncthreads();
#pragma unroll
        for (int kk = 0; kk < 16; kk++) {
            float4 av = *(const float4*)&As[kk][ty * 4];
            float4 bv = *(const float4*)&Bs[kk][tx * 4];
            float a[4] = {av.x, av.y, av.z, av.w};
            float b[4] = {bv.x, bv.y, bv.z, bv.w};
#pragma unroll
            for (int i = 0; i < 4; i++)
#pragma unroll
                for (int j = 0; j < 4; j++)
                    acc[i][j] = fmaf(a[i], b[j], acc[i][j]);
        }
    }

#pragma unroll
    for (int i = 0; i < 4; i++) {
        const int m = m0 + ty * 4 + i;
#pragma unroll
        for (int j = 0; j < 4; j++) {
            const int n = n0 + tx * 4 + j;
            const float v = acc[i][j] + bias[n];
            if (MODE == 0) {
                const int b = m / LL, l = m % LL;
                const int h = n / HD, d = n % HD;
                out[(((size_t)b * NH + h) * LL + l) * HD + d] = v;
            } else {
                out[(size_t)m * N + n] = v;
            }
        }
    }
}

// ---------------------------------------------------------------------------
// Attention: score_np (producer) + select_np (consumer); split (R7) killed
// the structural 64-reg live range that spilled in v3-v6.
//
// score_np v3 (R9): 4 rows x 4 keys per lane. R8-v2 was LDS-read bound:
// 80 b128 reads per 256 FMA wave-insts (q re-read from LDS every tile;
// sustainable ratio is ~8 FMA/b128, we were at 3.2). Now a wave covers
// 256 keys/pass (key = j*64+lane): per d4 it reads 4 q + 4 k float4s and
// does 64 FMAs -> ratio 8, balanced. K staged single-buffered 256 rows
// (68 KB, +4 pad keeps the free 2-way bank pattern), 8 passes, 2 barriers
// each. acc[4][4] float4 lives only WITHIN one pass (R0-proven short
// live-range shape). Per-(row,key) chain ops/order IDENTICAL (t asc, sub
// desc, x/y/z/w chains, ((x+y)+(z+w))*0.125) -> bit-exact.
// select_np: R0-proven consumer; mv[32] short live range -> registers.
// ---------------------------------------------------------------------------
__global__ __launch_bounds__(256) void score_np(
    const float* __restrict__ Qf, const float* __restrict__ Kf,
    unsigned* __restrict__ scw, int bh0)
{
#pragma clang fp contract(off)
    const int tid  = threadIdx.x;
    const int lane = tid & 63;
    const int wv   = tid >> 6;
    const int l0   = blockIdx.x * 16;
    const int bhl  = blockIdx.y;
    const int bh   = bh0 + bhl;

    __shared__ float kt[256][68];      // 68 KB: 256 K-rows (+4 pad per row)
    __shared__ float qsh[16][64];      // 4 KB

    const float* __restrict__ Kb = Kf + (size_t)bh * LL * HD;

    // stage q rows: 256 threads = 16 rows x 16 float4, one each
    {
        const int r = tid >> 4, d4q = tid & 15;
        *(float4*)&qsh[r][d4q * 4] =
            *(const float4*)&Qf[((size_t)bh * LL + l0 + r) * HD + d4q * 4];
    }

    const int r0 = wv * 4;
    unsigned* __restrict__ s0 = scw + ((size_t)bhl * LL + l0 + r0 + 0) * LL;
    unsigned* __restrict__ s1 = scw + ((size_t)bhl * LL + l0 + r0 + 1) * LL;
    unsigned* __restrict__ s2 = scw + ((size_t)bhl * LL + l0 + r0 + 2) * LL;
    unsigned* __restrict__ s3 = scw + ((size_t)bhl * LL + l0 + r0 + 3) * LL;

    for (int kp = 0; kp < 8; kp++) {
        // barrier 1: prev pass's kt reads done (1st iter: qsh staged)
        __syncthreads();
        // stage 256 K-rows: thread t owns row kp*256+t (16 coalesced b128)
        {
            const float* src = Kb + ((size_t)kp * 256 + tid) * HD;
#pragma unroll
            for (int i = 0; i < 16; i++)
                *(float4*)&kt[tid][i * 4] = *(const float4*)&src[i * 4];
        }
        __syncthreads();   // barrier 2: kt ready

        // 4 rows x 4 keys per lane; keys = kp*256 + j*64 + lane
        float4 acc[4][4];
#pragma unroll
        for (int r = 0; r < 4; r++)
#pragma unroll
            for (int j = 0; j < 4; j++)
                acc[r][j] = make_float4(0.f, 0.f, 0.f, 0.f);

#pragma unroll
        for (int t = 0; t < 4; t++) {
#pragma unroll
            for (int sub = 3; sub >= 0; sub--) {
                const int d4 = 4 * t + sub;
                float4 kf0 = *(const float4*)&kt[0 * 64 + lane][d4 * 4];
                float4 kf1 = *(const float4*)&kt[1 * 64 + lane][d4 * 4];
                float4 kf2 = *(const float4*)&kt[2 * 64 + lane][d4 * 4];
                float4 kf3 = *(const float4*)&kt[3 * 64 + lane][d4 * 4];
                float4 qv0 = *(const float4*)&qsh[r0 + 0][d4 * 4];
                float4 qv1 = *(const float4*)&qsh[r0 + 1][d4 * 4];
                float4 qv2 = *(const float4*)&qsh[r0 + 2][d4 * 4];
                float4 qv3 = *(const float4*)&qsh[r0 + 3][d4 * 4];
#pragma unroll
                for (int r = 0; r < 4; r++) {
                    const float4 q = (r == 0) ? qv0 : (r == 1) ? qv1
                                   : (r == 2) ? qv2 : qv3;
#pragma unroll
                    for (int j = 0; j < 4; j++) {
                        const float4 k = (j == 0) ? kf0 : (j == 1) ? kf1
                                       : (j == 2) ? kf2 : kf3;
                        acc[r][j].x = q.x * k.x + acc[r][j].x;
                        acc[r][j].y = q.y * k.y + acc[r][j].y;
                        acc[r][j].z = q.z * k.z + acc[r][j].z;
                        acc[r][j].w = q.w * k.w + acc[r][j].w;
                    }
                }
            }
        }

        // stores: coalesced (lane-consecutive) per (row, j)
#pragma unroll
        for (int j = 0; j < 4; j++) {
            const int kk = kp * 256 + j * 64 + lane;
            s0[kk] = mono32(((acc[0][j].x + acc[0][j].y) +
                             (acc[0][j].z + acc[0][j].w)) * 0.125f);
            s1[kk] = mono32(((acc[1][j].x + acc[1][j].y) +
                             (acc[1][j].z + acc[1][j].w)) * 0.125f);
            s2[kk] = mono32(((acc[2][j].x + acc[2][j].y) +
                             (acc[2][j].z + acc[2][j].w)) * 0.125f);
            s3[kk] = mono32(((acc[3][j].x + acc[3][j].y) +
                             (acc[3][j].z + acc[3][j].w)) * 0.125f);
        }
    }
}

__global__ __launch_bounds__(256) void select_np(
    const unsigned* __restrict__ scw, const float* __restrict__ Vf,
    float* __restrict__ ctx, int U, int bh0)
{
#pragma clang fp contract(off)
    const int tid  = threadIdx.x;
    const int lane = tid & 63;
    const int wv   = tid >> 6;
    const int l0   = blockIdx.x * 8;
    const int bhl  = blockIdx.y;
    const int bh   = bh0 + bhl;
    const int b    = bh / NH;
    const int h    = bh % NH;

    __shared__ float wls[8][64];       // 2 KB
    __shared__ int   kls[8][64];       // 2 KB

    const unsigned long long laneLT = (1ull << lane) - 1ull;
    const float* __restrict__ Vb = Vf + (size_t)bh * LL * HD;

#pragma unroll
    for (int rr8 = 0; rr8 < 2; rr8++) {
        const int rr = wv * 2 + rr8;
        const unsigned* __restrict__ srow =
            scw + ((size_t)bhl * LL + l0 + rr) * LL;

        // own-lane scores, coalesced load; SHORT live range -> registers
        unsigned mv[32];
#pragma unroll
        for (int j = 0; j < 32; j++) mv[j] = srow[lane + 64 * j];

        // exact U-th-largest key (largest T with count(>=T) >= U)
        unsigned lo = 0u, hi = 0xFFFFFFFFu;
        while (lo < hi) {
            const unsigned span = hi - lo;
            const unsigned mid = lo + (span >> 1) + (span & 1u);
            int c = 0;
#pragma unroll
            for (int j = 0; j < 32; j++)
                c += (int)__popcll(__ballot(mv[j] >= mid));
            if (c >= U) lo = mid; else hi = mid - 1u;
        }

        // max kept (reduce in key domain; lanes w/o kept contribute 0)
        unsigned mk = 0;
#pragma unroll
        for (int j = 0; j < 32; j++)
            if (mv[j] >= lo) mk = (mv[j] > mk) ? mv[j] : mk;
#pragma unroll
        for (int off = 32; off > 0; off >>= 1) {
            const unsigned o = __shfl_xor(mk, off, 64);
            mk = (o > mk) ? o : mk;
        }
        const float mx = unmono32(mk);

        // compact kept (index order)
        int n = 0;
#pragma unroll
        for (int j = 0; j < 32; j++) {
            const bool p = (mv[j] >= lo);
            const unsigned long long ball = __ballot(p);
            if (p) {
                const int pos = n + (int)__popcll(ball & laneLT);
                if (pos < 64) {
                    kls[rr][pos] = lane + 64 * j;
                    wls[rr][pos] = expf(unmono32(mv[j]) - mx);
                }
            }
            n += (int)__popcll(ball);
        }
        if (n > 64) n = 64;

        float dl = (lane < n) ? wls[rr][lane] : 0.0f;
#pragma unroll
        for (int off = 32; off > 0; off >>= 1) dl += __shfl_xor(dl, off, 64);
        const float rden = 1.0f / dl;

        float acc = 0.0f;
        for (int c = 0; c < n; c++)
            acc = fmaf(wls[rr][c], Vb[(size_t)kls[rr][c] * HD + lane], acc);

        ctx[((size_t)b * LL + l0 + rr) * DM + h * HD + lane] = acc * rden;
    }
}

// ---------------------------------------------------------------------------
extern "C" void kernel_launch(void* const* d_in, const int* in_sizes, int n_in,
                              void* d_out, int out_size, void* d_ws, size_t ws_size,
                              hipStream_t stream)
{
    const float* x  = (const float*)d_in[0];
    const float* Wq = (const float*)d_in[1];
    const float* bq = (const float*)d_in[2];
    const float* Wk = (const float*)d_in[3];
    const float* bk = (const float*)d_in[4];
    const float* Wv = (const float*)d_in[5];
    const float* bv = (const float*)d_in[6];
    const float* Wo = (const float*)d_in[7];
    const float* bo = (const float*)d_in[8];
    float* out = (float*)d_out;

    const size_t E = (size_t)BB * NH * LL * HD;   // 4M elements
    float* Wt1 = (float*)d_ws;                    // 4 MB
    float* Wt2 = Wt1 + (size_t)DM * DM;           // 4 MB
    float* Qf  = Wt2 + (size_t)DM * DM;           // 16 MB
    float* Kf  = Qf + E;                          // 16 MB
    float* Vf  = Kf + E;                          // 16 MB
    float* ctx = Vf + E;                          // 16 MB   (72 MB total)
    unsigned* scw = (unsigned*)(ctx + E);         // scores chunks (<=128 MB)

    int U = (int)(5.0 * log((double)LL));
    if (U > LL) U = LL;

    // chunk size in (b,h) panels, bounded by remaining workspace
    const size_t base_bytes = (size_t)72 * 1024 * 1024;
    const size_t per_bh = (size_t)LL * LL * 4;    // 16 MB per panel
    size_t avail = (ws_size > base_bytes) ? (ws_size - base_bytes) : 0;
    int chunk = (int)(avail / per_bh);
    if (chunk < 1) chunk = 1;
    if (chunk > 8) chunk = 8;

    const int M = BB * LL;  // 4096
    dim3 blk(256);
    dim3 gT(DM / 32, DM / 32);
    dim3 gP(M / 8);
    dim3 g64(DM / 64, M / 64);

    hipLaunchKernelGGL(transpose1024, gT, blk, 0, stream, Wq, Wt1);
    hipLaunchKernelGGL(transpose1024, gT, blk, 0, stream, Wk, Wt2);
    hipLaunchKernelGGL(proj_emul, gP, blk, 0, stream, x, Wt1, bq, Qf);
    hipLaunchKernelGGL(proj_emul, gP, blk, 0, stream, x, Wt2, bk, Kf);
    hipLaunchKernelGGL((gemm_f32<0>), g64, blk, 0, stream, x, Wv, bv, Vf, M, DM, DM);

    for (int bh0 = 0; bh0 < BB * NH; bh0 += chunk) {
        int nb = BB * NH - bh0;
        if (nb > chunk) nb = chunk;
        dim3 gA(LL / 16, nb);
        dim3 gS(LL / 8, nb);
        hipLaunchKernelGGL(score_np,  gA, blk, 0, stream, Qf, Kf, scw, bh0);
        hipLaunchKernelGGL(select_np, gS, blk, 0, stream, scw, Vf, ctx, U, bh0);
    }

    hipLaunchKernelGGL((gemm_f32<1>), g64, blk, 0, stream, ctx, Wo, bo, out, M, DM, DM);
}

// Round 10
// 1867.703 us; speedup vs baseline: 1.0681x; 1.0681x over previous
//
#include <hip/hip_runtime.h>
#include <math.h>

#define BB 2
#define LL 2048
#define DM 1024
#define NH 16
#define HD 64

__device__ __forceinline__ unsigned mono32(float f) {
    unsigned u = __float_as_uint(f);
    return (u & 0x80000000u) ? ~u : (u | 0x80000000u);
}
__device__ __forceinline__ float unmono32(unsigned m) {
    const unsigned u = (m & 0x80000000u) ? (m & 0x7FFFFFFFu) : ~m;
    return __uint_as_float(u);
}

// ---------------------------------------------------------------------------
// 1024x1024 transpose: out[k][n] = in[n][k]
// ---------------------------------------------------------------------------
__global__ __launch_bounds__(256) void transpose1024(
    const float* __restrict__ in, float* __restrict__ out)
{
    __shared__ float t[32][33];
    const int bx = blockIdx.x * 32, by = blockIdx.y * 32;
    const int tx = threadIdx.x & 31, ty = threadIdx.x >> 5;
    for (int r = ty; r < 32; r += 8)
        t[r][tx] = in[(size_t)(by + r) * DM + bx + tx];
    __syncthreads();
    for (int r = ty; r < 32; r += 8)
        out[(size_t)(bx + r) * DM + by + tx] = t[tx][r];
}

// ---------------------------------------------------------------------------
// Bit-emulated f32 projection (numpy -> OpenBLAS sgemm, Zen/Haswell):
// K-panels (384,320,320); serial ascending-k FMA chain per panel; C += panel;
// then +bias. Scatter to [B,H,L,D]. Wt is W transposed [k][n].
// v2: 4 columns/thread (float4 W loads) + float4 LDS x reads; per-output
// fmaf chain IDENTICAL (k ascending per (m,n), panel C+= order kept).
// DO NOT TOUCH chain order: Q/K bit-exactness determines top-k selection.
// ---------------------------------------------------------------------------
__global__ __launch_bounds__(256) void proj_emul(
    const float* __restrict__ x, const float* __restrict__ Wt,
    const float* __restrict__ bias, float* __restrict__ outp)
{
    __shared__ float xs[8][DM];   // 32 KB
    const int tid = threadIdx.x;
    const int n4  = tid * 4;                 // 4 consecutive cols per thread
    const int m0  = blockIdx.x * 8;

    for (int i = tid; i < 8 * 256; i += 256) {
        const int r = i >> 8, c4 = (i & 255) << 2;
        *(float4*)&xs[r][c4] = *(const float4*)&x[(size_t)(m0 + r) * DM + c4];
    }
    __syncthreads();

    const int kbound[4] = {0, 384, 704, 1024};   // OpenBLAS Zen panel splits

    float S[8][4] = {};
#pragma unroll
    for (int p = 0; p < 3; p++) {
        float P[8][4] = {};
        for (int k = kbound[p]; k < kbound[p + 1]; k += 4) {
            const float4 w0 = *(const float4*)&Wt[(size_t)(k + 0) * DM + n4];
            const float4 w1 = *(const float4*)&Wt[(size_t)(k + 1) * DM + n4];
            const float4 w2 = *(const float4*)&Wt[(size_t)(k + 2) * DM + n4];
            const float4 w3 = *(const float4*)&Wt[(size_t)(k + 3) * DM + n4];
#pragma unroll
            for (int m = 0; m < 8; m++) {
                const float4 xv = *(const float4*)&xs[m][k];
                P[m][0] = fmaf(xv.x, w0.x, P[m][0]);
                P[m][1] = fmaf(xv.x, w0.y, P[m][1]);
                P[m][2] = fmaf(xv.x, w0.z, P[m][2]);
                P[m][3] = fmaf(xv.x, w0.w, P[m][3]);
                P[m][0] = fmaf(xv.y, w1.x, P[m][0]);
                P[m][1] = fmaf(xv.y, w1.y, P[m][1]);
                P[m][2] = fmaf(xv.y, w1.z, P[m][2]);
                P[m][3] = fmaf(xv.y, w1.w, P[m][3]);
                P[m][0] = fmaf(xv.z, w2.x, P[m][0]);
                P[m][1] = fmaf(xv.z, w2.y, P[m][1]);
                P[m][2] = fmaf(xv.z, w2.z, P[m][2]);
                P[m][3] = fmaf(xv.z, w2.w, P[m][3]);
                P[m][0] = fmaf(xv.w, w3.x, P[m][0]);
                P[m][1] = fmaf(xv.w, w3.y, P[m][1]);
                P[m][2] = fmaf(xv.w, w3.z, P[m][2]);
                P[m][3] = fmaf(xv.w, w3.w, P[m][3]);
            }
        }
#pragma unroll
        for (int m = 0; m < 8; m++) {
#pragma unroll
            for (int j = 0; j < 4; j++) S[m][j] += P[m][j];  // C += panel
        }
    }

    const float4 b4v = *(const float4*)&bias[n4];
    const int h = n4 / HD, d0 = n4 % HD;   // 4 cols stay in one head
#pragma unroll
    for (int m = 0; m < 8; m++) {
        const int mm = m0 + m;
        const int b = mm / LL, l = mm % LL;
        float4 o;
        o.x = S[m][0] + b4v.x; o.y = S[m][1] + b4v.y;
        o.z = S[m][2] + b4v.z; o.w = S[m][3] + b4v.w;
        *(float4*)&outp[(((size_t)b * NH + h) * LL + l) * HD + d0] = o;
    }
}

// ---------------------------------------------------------------------------
// f32 GEMM for V (MODE 0 scatter) and output projection (MODE 1).
// ---------------------------------------------------------------------------
template <int MODE>
__global__ __launch_bounds__(256) void gemm_f32(
    const float* __restrict__ A, const float* __restrict__ W,
    const float* __restrict__ bias, float* __restrict__ out,
    int M, int N, int K)
{
    __shared__ float As[16][64];
    __shared__ float Bs[16][64];
    const int tid = threadIdx.x;
    const int m0 = blockIdx.y * 64;
    const int n0 = blockIdx.x * 64;
    const int tx = tid & 15, ty = tid >> 4;
    const int lr = tid >> 2, lc = (tid & 3) * 4;

    float acc[4][4] = {};

    for (int k0 = 0; k0 < K; k0 += 16) {
        float4 a4 = *(const float4*)&A[(size_t)(m0 + lr) * K + k0 + lc];
        float4 b4 = *(const float4*)&W[(size_t)(n0 + lr) * K + k0 + lc];
        __syncthreads();
        As[lc + 0][lr] = a4.x; As[lc + 1][lr] = a4.y;
        As[lc + 2][lr] = a4.z; As[lc + 3][lr] = a4.w;
        Bs[lc + 0][lr] = b4.x; Bs[lc + 1][lr] = b4.y;
        Bs[lc + 2][lr] = b4.z; Bs[lc + 3][lr] = b4.w;
        __syncthreads();
#pragma unroll
        for (int kk = 0; kk < 16; kk++) {
            float4 av = *(const float4*)&As[kk][ty * 4];
            float4 bv = *(const float4*)&Bs[kk][tx * 4];
            float a[4] = {av.x, av.y, av.z, av.w};
            float b[4] = {bv.x, bv.y, bv.z, bv.w};
#pragma unroll
            for (int i = 0; i < 4; i++)
#pragma unroll
                for (int j = 0; j < 4; j++)
                    acc[i][j] = fmaf(a[i], b[j], acc[i][j]);
        }
    }

#pragma unroll
    for (int i = 0; i < 4; i++) {
        const int m = m0 + ty * 4 + i;
#pragma unroll
        for (int j = 0; j < 4; j++) {
            const int n = n0 + tx * 4 + j;
            const float v = acc[i][j] + bias[n];
            if (MODE == 0) {
                const int b = m / LL, l = m % LL;
                const int h = n / HD, d = n % HD;
                out[(((size_t)b * NH + h) * LL + l) * HD + d] = v;
            } else {
                out[(size_t)m * N + n] = v;
            }
        }
    }
}

// ---------------------------------------------------------------------------
// Attention: score_np (producer) + select_np (consumer); split (R7) killed
// the structural 64-reg live range that spilled in v3-v6.
//
// score_np v4 (R10): 4 rows x 2 keys per lane, 128-row K tile.
//   R9-v3 regressed (261 vs 183 µs): kt[256][68]=72KB LDS rounded past
//   80KB/block -> 1 block/CU (occ 11.6%), AND per-thread-row staging
//   destroyed coalescing (lane stride 256B -> 64 cache lines/inst,
//   VALU 65->40%). v4 keeps the FMA:LDS-read ratio gain (48 vs v2's 80
//   b128-insts per 64 keys) at v2's PROVEN footprint: LDS 38912 (2
//   blocks/CU measured), idx-based coalesced staging, prefetch-to-regs
//   issued before compute (HBM latency hides under FMAs).
//   Per-(row,key) chain ops/order IDENTICAL (t asc, sub desc, x/y/z/w,
//   ((x+y)+(z+w))*0.125) -> bit-exact.
// select_np: R0-proven consumer; mv[32] short live range -> registers.
// ---------------------------------------------------------------------------
__global__ __launch_bounds__(256) void score_np(
    const float* __restrict__ Qf, const float* __restrict__ Kf,
    unsigned* __restrict__ scw, int bh0)
{
#pragma clang fp contract(off)
    const int tid  = threadIdx.x;
    const int lane = tid & 63;
    const int wv   = tid >> 6;
    const int l0   = blockIdx.x * 16;
    const int bhl  = blockIdx.y;
    const int bh   = bh0 + bhl;

    __shared__ float kt[128][68];      // 34 KB: 128 K-rows (+4 pad per row)
    __shared__ float qsh[16][64];      // 4 KB

    const float* __restrict__ Kb = Kf + (size_t)bh * LL * HD;

    // stage q rows: 256 threads = 16 rows x 16 float4, one each
    {
        const int r = tid >> 4, d4q = tid & 15;
        *(float4*)&qsh[r][d4q * 4] =
            *(const float4*)&Qf[((size_t)bh * LL + l0 + r) * HD + d4q * 4];
    }
    // stage K pass 0: idx-coalesced (consecutive tid -> consecutive 16B)
#pragma unroll
    for (int i = 0; i < 8; i++) {
        const int idx = i * 256 + tid;
        *(float4*)&kt[idx >> 4][(idx & 15) * 4] =
            *(const float4*)&Kb[(size_t)(idx >> 4) * HD + (idx & 15) * 4];
    }
    __syncthreads();

    const int r0 = wv * 4;
    unsigned* __restrict__ s0 = scw + ((size_t)bhl * LL + l0 + r0 + 0) * LL;
    unsigned* __restrict__ s1 = scw + ((size_t)bhl * LL + l0 + r0 + 1) * LL;
    unsigned* __restrict__ s2 = scw + ((size_t)bhl * LL + l0 + r0 + 2) * LL;
    unsigned* __restrict__ s3 = scw + ((size_t)bhl * LL + l0 + r0 + 3) * LL;

    for (int kp = 0; kp < 16; kp++) {
        // prefetch next pass to regs (issued BEFORE compute; latency hides)
        float4 pf[8];
        if (kp < 15) {
            const float* src = Kb + (size_t)(kp + 1) * 128 * HD;
#pragma unroll
            for (int i = 0; i < 8; i++) {
                const int idx = i * 256 + tid;
                pf[i] = *(const float4*)&src[(size_t)(idx >> 4) * HD +
                                             (idx & 15) * 4];
            }
        }

        // 4 rows x 2 keys per lane; keys = kp*128 + j*64 + lane
        float4 a00 = {0,0,0,0}, a01 = {0,0,0,0};
        float4 a10 = {0,0,0,0}, a11 = {0,0,0,0};
        float4 a20 = {0,0,0,0}, a21 = {0,0,0,0};
        float4 a30 = {0,0,0,0}, a31 = {0,0,0,0};
#pragma unroll
        for (int t = 0; t < 4; t++) {
#pragma unroll
            for (int sub = 3; sub >= 0; sub--) {
                const int d4 = 4 * t + sub;
                const float4 k0 = *(const float4*)&kt[0 * 64 + lane][d4 * 4];
                const float4 k1 = *(const float4*)&kt[1 * 64 + lane][d4 * 4];
                const float4 q0 = *(const float4*)&qsh[r0 + 0][d4 * 4];
                const float4 q1 = *(const float4*)&qsh[r0 + 1][d4 * 4];
                const float4 q2 = *(const float4*)&qsh[r0 + 2][d4 * 4];
                const float4 q3 = *(const float4*)&qsh[r0 + 3][d4 * 4];
                a00.x = q0.x * k0.x + a00.x; a00.y = q0.y * k0.y + a00.y;
                a00.z = q0.z * k0.z + a00.z; a00.w = q0.w * k0.w + a00.w;
                a01.x = q0.x * k1.x + a01.x; a01.y = q0.y * k1.y + a01.y;
                a01.z = q0.z * k1.z + a01.z; a01.w = q0.w * k1.w + a01.w;
                a10.x = q1.x * k0.x + a10.x; a10.y = q1.y * k0.y + a10.y;
                a10.z = q1.z * k0.z + a10.z; a10.w = q1.w * k0.w + a10.w;
                a11.x = q1.x * k1.x + a11.x; a11.y = q1.y * k1.y + a11.y;
                a11.z = q1.z * k1.z + a11.z; a11.w = q1.w * k1.w + a11.w;
                a20.x = q2.x * k0.x + a20.x; a20.y = q2.y * k0.y + a20.y;
                a20.z = q2.z * k0.z + a20.z; a20.w = q2.w * k0.w + a20.w;
                a21.x = q2.x * k1.x + a21.x; a21.y = q2.y * k1.y + a21.y;
                a21.z = q2.z * k1.z + a21.z; a21.w = q2.w * k1.w + a21.w;
                a30.x = q3.x * k0.x + a30.x; a30.y = q3.y * k0.y + a30.y;
                a30.z = q3.z * k0.z + a30.z; a30.w = q3.w * k0.w + a30.w;
                a31.x = q3.x * k1.x + a31.x; a31.y = q3.y * k1.y + a31.y;
                a31.z = q3.z * k1.z + a31.z; a31.w = q3.w * k1.w + a31.w;
            }
        }

        // stores: coalesced (lane-consecutive) per (row, j)
        const int kkA = kp * 128 + lane;
        const int kkB = kp * 128 + 64 + lane;
        s0[kkA] = mono32(((a00.x + a00.y) + (a00.z + a00.w)) * 0.125f);
        s0[kkB] = mono32(((a01.x + a01.y) + (a01.z + a01.w)) * 0.125f);
        s1[kkA] = mono32(((a10.x + a10.y) + (a10.z + a10.w)) * 0.125f);
        s1[kkB] = mono32(((a11.x + a11.y) + (a11.z + a11.w)) * 0.125f);
        s2[kkA] = mono32(((a20.x + a20.y) + (a20.z + a20.w)) * 0.125f);
        s2[kkB] = mono32(((a21.x + a21.y) + (a21.z + a21.w)) * 0.125f);
        s3[kkA] = mono32(((a30.x + a30.y) + (a30.z + a30.w)) * 0.125f);
        s3[kkB] = mono32(((a31.x + a31.y) + (a31.z + a31.w)) * 0.125f);

        if (kp < 15) {
            __syncthreads();   // all reads of kt done
#pragma unroll
            for (int i = 0; i < 8; i++) {
                const int idx = i * 256 + tid;
                *(float4*)&kt[idx >> 4][(idx & 15) * 4] = pf[i];
            }
            __syncthreads();   // kt ready for next pass
        }
    }
}

__global__ __launch_bounds__(256) void select_np(
    const unsigned* __restrict__ scw, const float* __restrict__ Vf,
    float* __restrict__ ctx, int U, int bh0)
{
#pragma clang fp contract(off)
    const int tid  = threadIdx.x;
    const int lane = tid & 63;
    const int wv   = tid >> 6;
    const int l0   = blockIdx.x * 8;
    const int bhl  = blockIdx.y;
    const int bh   = bh0 + bhl;
    const int b    = bh / NH;
    const int h    = bh % NH;

    __shared__ float wls[8][64];       // 2 KB
    __shared__ int   kls[8][64];       // 2 KB

    const unsigned long long laneLT = (1ull << lane) - 1ull;
    const float* __restrict__ Vb = Vf + (size_t)bh * LL * HD;

#pragma unroll
    for (int rr8 = 0; rr8 < 2; rr8++) {
        const int rr = wv * 2 + rr8;
        const unsigned* __restrict__ srow =
            scw + ((size_t)bhl * LL + l0 + rr) * LL;

        // own-lane scores, coalesced load; SHORT live range -> registers
        unsigned mv[32];
#pragma unroll
        for (int j = 0; j < 32; j++) mv[j] = srow[lane + 64 * j];

        // exact U-th-largest key (largest T with count(>=T) >= U)
        unsigned lo = 0u, hi = 0xFFFFFFFFu;
        while (lo < hi) {
            const unsigned span = hi - lo;
            const unsigned mid = lo + (span >> 1) + (span & 1u);
            int c = 0;
#pragma unroll
            for (int j = 0; j < 32; j++)
                c += (int)__popcll(__ballot(mv[j] >= mid));
            if (c >= U) lo = mid; else hi = mid - 1u;
        }

        // max kept (reduce in key domain; lanes w/o kept contribute 0)
        unsigned mk = 0;
#pragma unroll
        for (int j = 0; j < 32; j++)
            if (mv[j] >= lo) mk = (mv[j] > mk) ? mv[j] : mk;
#pragma unroll
        for (int off = 32; off > 0; off >>= 1) {
            const unsigned o = __shfl_xor(mk, off, 64);
            mk = (o > mk) ? o : mk;
        }
        const float mx = unmono32(mk);

        // compact kept (index order)
        int n = 0;
#pragma unroll
        for (int j = 0; j < 32; j++) {
            const bool p = (mv[j] >= lo);
            const unsigned long long ball = __ballot(p);
            if (p) {
                const int pos = n + (int)__popcll(ball & laneLT);
                if (pos < 64) {
                    kls[rr][pos] = lane + 64 * j;
                    wls[rr][pos] = expf(unmono32(mv[j]) - mx);
                }
            }
            n += (int)__popcll(ball);
        }
        if (n > 64) n = 64;

        float dl = (lane < n) ? wls[rr][lane] : 0.0f;
#pragma unroll
        for (int off = 32; off > 0; off >>= 1) dl += __shfl_xor(dl, off, 64);
        const float rden = 1.0f / dl;

        float acc = 0.0f;
        for (int c = 0; c < n; c++)
            acc = fmaf(wls[rr][c], Vb[(size_t)kls[rr][c] * HD + lane], acc);

        ctx[((size_t)b * LL + l0 + rr) * DM + h * HD + lane] = acc * rden;
    }
}

// ---------------------------------------------------------------------------
extern "C" void kernel_launch(void* const* d_in, const int* in_sizes, int n_in,
                              void* d_out, int out_size, void* d_ws, size_t ws_size,
                              hipStream_t stream)
{
    const float* x  = (const float*)d_in[0];
    const float* Wq = (const float*)d_in[1];
    const float* bq = (const float*)d_in[2];
    const float* Wk = (const float*)d_in[3];
    const float* bk = (const float*)d_in[4];
    const float* Wv = (const float*)d_in[5];
    const float* bv = (const float*)d_in[6];
    const float* Wo = (const float*)d_in[7];
    const float* bo = (const float*)d_in[8];
    float* out = (float*)d_out;

    const size_t E = (size_t)BB * NH * LL * HD;   // 4M elements
    float* Wt1 = (float*)d_ws;                    // 4 MB
    float* Wt2 = Wt1 + (size_t)DM * DM;           // 4 MB
    float* Qf  = Wt2 + (size_t)DM * DM;           // 16 MB
    float* Kf  = Qf + E;                          // 16 MB
    float* Vf  = Kf + E;                          // 16 MB
    float* ctx = Vf + E;                          // 16 MB   (72 MB total)
    unsigned* scw = (unsigned*)(ctx + E);         // scores chunks (<=128 MB)

    int U = (int)(5.0 * log((double)LL));
    if (U > LL) U = LL;

    // chunk size in (b,h) panels, bounded by remaining workspace
    const size_t base_bytes = (size_t)72 * 1024 * 1024;
    const size_t per_bh = (size_t)LL * LL * 4;    // 16 MB per panel
    size_t avail = (ws_size > base_bytes) ? (ws_size - base_bytes) : 0;
    int chunk = (int)(avail / per_bh);
    if (chunk < 1) chunk = 1;
    if (chunk > 8) chunk = 8;

    const int M = BB * LL;  // 4096
    dim3 blk(256);
    dim3 gT(DM / 32, DM / 32);
    dim3 gP(M / 8);
    dim3 g64(DM / 64, M / 64);

    hipLaunchKernelGGL(transpose1024, gT, blk, 0, stream, Wq, Wt1);
    hipLaunchKernelGGL(transpose1024, gT, blk, 0, stream, Wk, Wt2);
    hipLaunchKernelGGL(proj_emul, gP, blk, 0, stream, x, Wt1, bq, Qf);
    hipLaunchKernelGGL(proj_emul, gP, blk, 0, stream, x, Wt2, bk, Kf);
    hipLaunchKernelGGL((gemm_f32<0>), g64, blk, 0, stream, x, Wv, bv, Vf, M, DM, DM);

    for (int bh0 = 0; bh0 < BB * NH; bh0 += chunk) {
        int nb = BB * NH - bh0;
        if (nb > chunk) nb = chunk;
        dim3 gA(LL / 16, nb);
        dim3 gS(LL / 8, nb);
        hipLaunchKernelGGL(score_np,  gA, blk, 0, stream, Qf, Kf, scw, bh0);
        hipLaunchKernelGGL(select_np, gS, blk, 0, stream, scw, Vf, ctx, U, bh0);
    }

    hipLaunchKernelGGL((gemm_f32<1>), g64, blk, 0, stream, ctx, Wo, bo, out, M, DM, DM);
}